// Round 3
// baseline (516.429 us; speedup 1.0000x reference)
//
#include <hip/hip_runtime.h>
#include <stdint.h>

#define KD 2048
#define NROWS 16384

typedef float f32x4 __attribute__((ext_vector_type(4)));
typedef __bf16 bf16x8 __attribute__((ext_vector_type(8)));
typedef unsigned short u16x8 __attribute__((ext_vector_type(8)));

// out layout (f32 elements): scores[N][61] | deltas[N][240] | cos[N][60] | negcos[N][60] | negscr[N][60]
#define OFF_DELTAS 999424
#define OFF_COS    4931584
#define OFF_NEGC   5914624
#define OFF_NEGS   6897664

// round-to-nearest-even f32 -> bf16 bits
__device__ inline unsigned short f2bf(float f) {
  union { float f; unsigned u; } v; v.f = f;
  unsigned u = v.u;
  return (unsigned short)((u + 0x7FFFu + ((u >> 16) & 1u)) >> 16);
}

__device__ inline void gload_lds16(const void* g, void* l) {
  __builtin_amdgcn_global_load_lds(
      (const __attribute__((address_space(1))) void*)g,
      (__attribute__((address_space(3))) void*)l,
      16, 0, 0);
}

// ---------------------------------------------------------------------------
// C[M x Npad] = A[M x 2048] @ B[Npad x 2048]^T   (f32 acc)
// 128x128 tile, BK=64, 4 waves (2x2), B via global_load_lds w=16.
// CONVA: A is f32, converted to bf16 during staging (reg-staged, XOR-swizzled);
//        else A is bf16, staged via global_load_lds (linear).
// EPI 0: Hbf = bf16(acc + bias[col])              -> Cb (internal, bf16)
// EPI 1: out = f32 (acc + bias[col]), col < Ncols -> Cf (deltas)
// EPI 2: out = f32 (acc * invn[row])              -> Cf (cos/neg dots)
// ---------------------------------------------------------------------------
template<int EPI, bool CONVA>
__global__ __launch_bounds__(256)
void gemm_bt(const void* __restrict__ Av,
             const unsigned short* __restrict__ B,
             unsigned short* __restrict__ Cb,
             float* __restrict__ Cf,
             const float* __restrict__ bias,
             const float* __restrict__ invn,
             int nNtiles, int Ncols, int ldc)
{
  __shared__ unsigned short sA[128 * 64];
  __shared__ unsigned short sB[128 * 64];
  const int bid = blockIdx.x;
  const int bm = bid / nNtiles, bn = bid % nNtiles;   // N fastest: co-resident blocks share B + A-row slice
  const size_t row0 = (size_t)bm * 128, col0 = (size_t)bn * 128;
  const int tid = threadIdx.x, lane = tid & 63, wv = tid >> 6;
  const char* Bb = (const char*)(B + col0 * KD);
  const int wr = (wv >> 1) * 64, wc = (wv & 1) * 64;  // 2x2 wave grid
  const int fr = lane & 15, fq = lane >> 4;
  f32x4 acc[4][4] = {};

  const int so = wv * 1024 + lane * 16;  // per-wave contiguous 1KB chunk

  // CONVA thread mapping: row = tid>>1 (0..127), half = tid&1 (k-offset half*32)
  const int arow = tid >> 1, ahalf = tid & 1;
  const float* Af = (const float*)Av;
  const char*  Ab = (const char*)Av;   // bf16 path

  for (int kt = 0; kt < KD / 64; ++kt) {
    const int kbyte = kt * 128;
    // ---- stage B (always gload_lds, linear) ----
#pragma unroll
    for (int i = 0; i < 4; ++i) {
      const int o = i * 4096 + so;
      const int r = o >> 7, cb = o & 127;
      gload_lds16(Bb + (size_t)r * (KD * 2) + kbyte + cb, (char*)sB + o);
    }
    // ---- stage A ----
    if (CONVA) {
      const float* ap = Af + (row0 + arow) * (size_t)KD + kt * 64 + ahalf * 32;
      float4 f[8];
#pragma unroll
      for (int j = 0; j < 8; ++j) f[j] = ((const float4*)ap)[j];
#pragma unroll
      for (int j = 0; j < 4; ++j) {
        u16x8 o;
        o[0] = f2bf(f[2*j].x);   o[1] = f2bf(f[2*j].y);
        o[2] = f2bf(f[2*j].z);   o[3] = f2bf(f[2*j].w);
        o[4] = f2bf(f[2*j+1].x); o[5] = f2bf(f[2*j+1].y);
        o[6] = f2bf(f[2*j+1].z); o[7] = f2bf(f[2*j+1].w);
        const int colb = (ahalf * 64 + j * 16) ^ ((arow & 7) << 4);  // XOR swizzle
        *(u16x8*)((char*)sA + arow * 128 + colb) = o;
      }
    } else {
#pragma unroll
      for (int i = 0; i < 4; ++i) {
        const int o = i * 4096 + so;
        const int r = o >> 7, cb = o & 127;
        gload_lds16(Ab + (size_t)r * (KD * 2) + kbyte + cb, (char*)sA + o);
      }
    }
    __syncthreads();   // drains vmcnt (gload_lds) + lgkmcnt (ds_write)
#pragma unroll
    for (int kk = 0; kk < 2; ++kk) {
      bf16x8 af[4], bfr[4];
#pragma unroll
      for (int m = 0; m < 4; ++m) {
        const int r = wr + m * 16 + fr;
        const int colb = kk * 64 + fq * 16;
        const int off = CONVA ? (colb ^ ((r & 7) << 4)) : colb;
        af[m] = *(const bf16x8*)((const char*)sA + r * 128 + off);
      }
#pragma unroll
      for (int n = 0; n < 4; ++n)
        bfr[n] = *(const bf16x8*)((const char*)sB + (wc + n * 16 + fr) * 128 + kk * 64 + fq * 16);
#pragma unroll
      for (int m = 0; m < 4; ++m)
#pragma unroll
        for (int n = 0; n < 4; ++n)
          acc[m][n] = __builtin_amdgcn_mfma_f32_16x16x32_bf16(af[m], bfr[n], acc[m][n], 0, 0, 0);
    }
    __syncthreads();
  }

  // epilogue: C/D frag layout col = lane&15, row = (lane>>4)*4 + j  [m89/m91]
#pragma unroll
  for (int m = 0; m < 4; ++m) {
    const size_t rb = row0 + wr + m * 16 + fq * 4;
#pragma unroll
    for (int n = 0; n < 4; ++n) {
      const int c = (int)col0 + wc + n * 16 + fr;
      if (EPI == 1 && c >= Ncols) continue;
      const float bv = (EPI == 0 || EPI == 1) ? bias[c] : 0.f;
#pragma unroll
      for (int j = 0; j < 4; ++j) {
        const size_t r = rb + j;
        const float v = acc[m][n][j];
        if (EPI == 0)      Cb[r * (size_t)ldc + c] = f2bf(v + bv);
        else if (EPI == 1) Cf[r * (size_t)ldc + c] = v + bv;
        else               Cf[r * (size_t)ldc + c] = v * invn[r];
      }
    }
  }
}

// x (f32) -> bf16 copy + per-row 1/max(||x||,eps)
__global__ __launch_bounds__(256)
void prep_x(const float* __restrict__ x, unsigned short* __restrict__ xbf,
            float* __restrict__ invn)
{
  const int n = blockIdx.x, tid = threadIdx.x;
  const float4* row = (const float4*)(x + (size_t)n * KD);
  float4 a = row[tid * 2], b = row[tid * 2 + 1];
  float ss = a.x * a.x + a.y * a.y + a.z * a.z + a.w * a.w
           + b.x * b.x + b.y * b.y + b.z * b.z + b.w * b.w;
#pragma unroll
  for (int off = 32; off > 0; off >>= 1) ss += __shfl_down(ss, off);
  __shared__ float red[4];
  if ((tid & 63) == 0) red[tid >> 6] = ss;
  __syncthreads();
  if (tid == 0) {
    const float tot = red[0] + red[1] + red[2] + red[3];
    invn[n] = 1.f / fmaxf(sqrtf(tot), 1e-8f);
  }
  u16x8 o;
  o[0] = f2bf(a.x); o[1] = f2bf(a.y); o[2] = f2bf(a.z); o[3] = f2bf(a.w);
  o[4] = f2bf(b.x); o[5] = f2bf(b.y); o[6] = f2bf(b.z); o[7] = f2bf(b.w);
  *(u16x8*)(xbf + (size_t)n * KD + (size_t)tid * 8) = o;
}

// per-row 1/max(||x||,eps) only (small-ws fallback; x not materialized as bf16)
__global__ __launch_bounds__(256)
void row_norms(const float* __restrict__ x, float* __restrict__ invn)
{
  const int n = blockIdx.x, tid = threadIdx.x;
  const float4* row = (const float4*)(x + (size_t)n * KD);
  float4 a = row[tid * 2], b = row[tid * 2 + 1];
  float ss = a.x * a.x + a.y * a.y + a.z * a.z + a.w * a.w
           + b.x * b.x + b.y * b.y + b.z * b.z + b.w * b.w;
#pragma unroll
  for (int off = 32; off > 0; off >>= 1) ss += __shfl_down(ss, off);
  __shared__ float red[4];
  if ((tid & 63) == 0) red[tid >> 6] = ss;
  __syncthreads();
  if (tid == 0) {
    const float tot = red[0] + red[1] + red[2] + red[3];
    invn[n] = 1.f / fmaxf(sqrtf(tot), 1e-8f);
  }
}

// reg_fc_w f32 -> bf16, 8 elems/thread (2048x2048 / 8 = 524288 threads)
__global__ __launch_bounds__(256)
void cvt_w1(const float* __restrict__ in, unsigned short* __restrict__ out)
{
  const size_t i = (size_t)blockIdx.x * 256 + threadIdx.x;
  const float4* p = (const float4*)(in + i * 8);
  float4 a = p[0], b = p[1];
  u16x8 o;
  o[0] = f2bf(a.x); o[1] = f2bf(a.y); o[2] = f2bf(a.z); o[3] = f2bf(a.w);
  o[4] = f2bf(b.x); o[5] = f2bf(b.y); o[6] = f2bf(b.z); o[7] = f2bf(b.w);
  *(u16x8*)(out + i * 8) = o;
}

// blocks 0..255: RN rows (0..59 reps normalized, 60..239 neg_reps normalized, pad zero)
// blocks 256..511: W2 rows (bbox_w bf16, pad zero)
__global__ __launch_bounds__(256)
void prep_rows(const float* __restrict__ reps, const float* __restrict__ negrep,
               const float* __restrict__ bbox,
               unsigned short* __restrict__ RN, unsigned short* __restrict__ W2)
{
  const int r = blockIdx.x, tid = threadIdx.x;
  const u16x8 z = {0, 0, 0, 0, 0, 0, 0, 0};
  if (r < 256) {
    unsigned short* dst = RN + (size_t)r * KD;
    if (r >= 240) { *(u16x8*)(dst + (size_t)tid * 8) = z; return; }
    const float* src = (r < 60) ? reps + (size_t)r * KD
                                : negrep + (size_t)(r - 60) * KD;
    const float4* p = (const float4*)src;
    float4 a = p[tid * 2], b = p[tid * 2 + 1];
    float ss = a.x * a.x + a.y * a.y + a.z * a.z + a.w * a.w
             + b.x * b.x + b.y * b.y + b.z * b.z + b.w * b.w;
#pragma unroll
    for (int off = 32; off > 0; off >>= 1) ss += __shfl_down(ss, off);
    __shared__ float red[4];
    if ((tid & 63) == 0) red[tid >> 6] = ss;
    __syncthreads();
    const float iv = 1.f / fmaxf(sqrtf(red[0] + red[1] + red[2] + red[3]), 1e-8f);
    u16x8 o;
    o[0] = f2bf(a.x * iv); o[1] = f2bf(a.y * iv); o[2] = f2bf(a.z * iv); o[3] = f2bf(a.w * iv);
    o[4] = f2bf(b.x * iv); o[5] = f2bf(b.y * iv); o[6] = f2bf(b.z * iv); o[7] = f2bf(b.w * iv);
    *(u16x8*)(dst + (size_t)tid * 8) = o;
  } else {
    const int rr = r - 256;
    unsigned short* dst = W2 + (size_t)rr * KD;
    if (rr >= 240) { *(u16x8*)(dst + (size_t)tid * 8) = z; return; }
    const float4* p = (const float4*)(bbox + (size_t)rr * KD);
    float4 a = p[tid * 2], b = p[tid * 2 + 1];
    u16x8 o;
    o[0] = f2bf(a.x); o[1] = f2bf(a.y); o[2] = f2bf(a.z); o[3] = f2bf(a.w);
    o[4] = f2bf(b.x); o[5] = f2bf(b.y); o[6] = f2bf(b.z); o[7] = f2bf(b.w);
    *(u16x8*)(dst + (size_t)tid * 8) = o;
  }
}

// S[n][0..59] = cos_sim (already *invnorm), S[n][60+3c+m] = neg dots; all outputs f32
__global__ __launch_bounds__(64)
void post(const float* __restrict__ S, float* __restrict__ out)
{
  const int n = blockIdx.x, c = threadIdx.x;
  const float* s = S + (size_t)n * 256;
  float* scores = out;
  float* cosv   = out + OFF_COS;
  float* negc   = out + OFF_NEGC;
  float* negs   = out + OFF_NEGS;
  if (c < 60) {
    const float cs = s[c];
    cosv[(size_t)n * 60 + c]   = cs;
    scores[(size_t)n * 61 + c] = expf(-(1.f - cs) * 20.f);
    const float m3 = fmaxf(s[60 + 3 * c], fmaxf(s[61 + 3 * c], s[62 + 3 * c]));
    negc[(size_t)n * 60 + c] = m3;
    negs[(size_t)n * 60 + c] = expf(-(1.f - m3) * 20.f);
  } else if (c == 60) {
    scores[(size_t)n * 61 + 60] = -100000.0f;
  }
}

extern "C" void kernel_launch(void* const* d_in, const int* in_sizes, int n_in,
                              void* d_out, int out_size, void* d_ws, size_t ws_size,
                              hipStream_t stream)
{
  const float* x      = (const float*)d_in[0];
  const float* reps   = (const float*)d_in[1];
  const float* negrep = (const float*)d_in[2];
  const float* w1     = (const float*)d_in[3];
  const float* b1     = (const float*)d_in[4];
  const float* w2     = (const float*)d_in[5];
  const float* b2     = (const float*)d_in[6];
  float* out = (float*)d_out;   // reference outputs are float32

  // ws carve — base 74.07 MiB; +64 MiB xbf if ws_size permits
  char* w = (char*)d_ws;
  unsigned short* Hbf  = (unsigned short*)(w);             // 64 MiB  [0, 67108864)
  unsigned short* W1bf = (unsigned short*)(w + 67108864);  // 8 MiB
  unsigned short* W2bf = (unsigned short*)(w + 75497472);  // 1 MiB
  unsigned short* RNbf = (unsigned short*)(w + 76546048);  // 1 MiB
  float*          invn = (float*)(w + 77594624);           // 64 KiB  (end 77660160)
  unsigned short* xbf  = (unsigned short*)(w + 77660160);  // 64 MiB  (end 144769024)
  float*          S    = (float*)w;  // reuse Hbf region: gemm<1> consumed Hbf before gemm<2> writes S

  const bool big = ws_size >= 144769024ull;   // deterministic across calls (graph-safe)

  cvt_w1<<<2048, 256, 0, stream>>>(w1, W1bf);
  prep_rows<<<512, 256, 0, stream>>>(reps, negrep, w2, RNbf, W2bf);

  if (big) {
    prep_x<<<NROWS, 256, 0, stream>>>(x, xbf, invn);
    // H = x @ W1^T + b1 (bf16 internal)
    gemm_bt<0, false><<<128 * 16, 256, 0, stream>>>(xbf, W1bf, Hbf, nullptr, b1, nullptr, 16, 2048, 2048);
    // deltas = H @ bbox^T + b2 -> out (f32)
    gemm_bt<1, false><<<128 * 2, 256, 0, stream>>>(Hbf, W2bf, nullptr, out + OFF_DELTAS, b2, nullptr, 2, 240, 240);
    // S = (x @ [rn;nrn]^T) * invn -> ws (f32)
    gemm_bt<2, false><<<128 * 2, 256, 0, stream>>>(xbf, RNbf, nullptr, S, nullptr, invn, 2, 256, 256);
  } else {
    row_norms<<<NROWS, 256, 0, stream>>>(x, invn);
    gemm_bt<0, true><<<128 * 16, 256, 0, stream>>>(x, W1bf, Hbf, nullptr, b1, nullptr, 16, 2048, 2048);
    gemm_bt<1, false><<<128 * 2, 256, 0, stream>>>(Hbf, W2bf, nullptr, out + OFF_DELTAS, b2, nullptr, 2, 240, 240);
    gemm_bt<2, true><<<128 * 2, 256, 0, stream>>>(x, RNbf, nullptr, S, nullptr, invn, 2, 256, 256);
  }
  post<<<NROWS, 64, 0, stream>>>(S, out);
}

// Round 4
// 467.488 us; speedup vs baseline: 1.1047x; 1.1047x over previous
//
#include <hip/hip_runtime.h>
#include <stdint.h>

#define KD 2048
#define NROWS 16384

typedef float f32x4 __attribute__((ext_vector_type(4)));
typedef __bf16 bf16x8 __attribute__((ext_vector_type(8)));
typedef unsigned short u16x8 __attribute__((ext_vector_type(8)));

// out layout (f32 elements): scores[N][61] | deltas[N][240] | cos[N][60] | negcos[N][60] | negscr[N][60]
#define OFF_DELTAS 999424
#define OFF_COS    4931584
#define OFF_NEGC   5914624
#define OFF_NEGS   6897664

// round-to-nearest-even f32 -> bf16 bits
__device__ inline unsigned short f2bf(float f) {
  union { float f; unsigned u; } v; v.f = f;
  unsigned u = v.u;
  return (unsigned short)((u + 0x7FFFu + ((u >> 16) & 1u)) >> 16);
}

__device__ inline void gload_lds16(const void* g, void* l) {
  __builtin_amdgcn_global_load_lds(
      (const __attribute__((address_space(1))) void*)g,
      (__attribute__((address_space(3))) void*)l,
      16, 0, 0);
}

// ===========================================================================
// gemm256: C[M x 2048] = A[M x 2048] @ B[2048 x 2048]^T, bf16 in, bf16 out.
// BM=256 BN=128 BK=64, 8 waves (4Mx2N, 64x64 each), 512 threads.
// 3-buffer LDS rotation (48KB/tile), prefetch depth 2, counted vmcnt(6):
//   per tile/wave: 4 A-gloads + 2 B-gloads = 6 vmcnt units.
//   boundary end-of-t: vmcnt(6) -> tile t+1 complete (only t+2's 6 remain).
// LDS XOR-swizzle byte^((row&7)<<4): applied on pre-swizzled GLOBAL source
// (gload_lds writes linearly; rule #21) and on the ds_read side.
// ===========================================================================
__global__ __launch_bounds__(512, 2)
void gemm256(const unsigned short* __restrict__ A,
             const unsigned short* __restrict__ B,
             unsigned short* __restrict__ Cb,
             const float* __restrict__ bias,
             int nNtiles, int ldc)
{
  __shared__ __align__(16) char lds[3 * 49152];   // 144 KiB (<=160 KiB/CU)
  const int bid = blockIdx.x;
  const int bm = bid / nNtiles, bn = bid % nNtiles;
  const size_t row0 = (size_t)bm * 256, col0 = (size_t)bn * 128;
  const int tid = threadIdx.x, lane = tid & 63, wv = tid >> 6;
  const int wm = wv >> 1, wn = wv & 1;           // 4x2 wave grid, 64x64 out per wave
  const int fr = lane & 15, fq = lane >> 4;
  const char* Ab = (const char*)(A + row0 * KD);
  const char* Bb = (const char*)(B + col0 * KD);
  f32x4 acc[4][4] = {};

  // staging chunk offsets (16B each); global col pre-swizzled so linear
  // gload_lds writes produce the swizzled LDS image
  int aoff[4], aG[4], boff[2], bG[2];
#pragma unroll
  for (int s = 0; s < 4; ++s) {
    const int o = (tid + s * 512) * 16;          // [0, 32768)
    const int r = o >> 7;
    aoff[s] = o;
    aG[s] = r * (KD * 2) + ((o & 127) ^ ((r & 7) << 4));
  }
#pragma unroll
  for (int s = 0; s < 2; ++s) {
    const int o = (tid + s * 512) * 16;          // [0, 16384)
    const int r = o >> 7;
    boff[s] = o;
    bG[s] = r * (KD * 2) + ((o & 127) ^ ((r & 7) << 4));
  }

  auto stage = [&](int kt, int b) {
    char* bufA = lds + b * 49152;
    char* bufB = bufA + 32768;
    const int kby = kt * 128;
#pragma unroll
    for (int s = 0; s < 4; ++s)
      gload_lds16(Ab + (size_t)(aG[s] + kby), bufA + aoff[s]);
#pragma unroll
    for (int s = 0; s < 2; ++s)
      gload_lds16(Bb + (size_t)(bG[s] + kby), bufB + boff[s]);
  };

  const int sw = (fr & 7) << 4;   // row&7 == fr&7 (rows offset by multiples of 8)

  auto compute = [&](int b) {
    const char* bufA = lds + b * 49152;
    const char* bufB = bufA + 32768;
    bf16x8 af[4][2], bfv[4][2];
#pragma unroll
    for (int m = 0; m < 4; ++m) {
      const char* base = bufA + (wm * 64 + m * 16 + fr) * 128;
#pragma unroll
      for (int kk = 0; kk < 2; ++kk)
        af[m][kk] = *(const bf16x8*)(base + ((kk * 64 + fq * 16) ^ sw));
    }
#pragma unroll
    for (int n = 0; n < 4; ++n) {
      const char* base = bufB + (wn * 64 + n * 16 + fr) * 128;
#pragma unroll
      for (int kk = 0; kk < 2; ++kk)
        bfv[n][kk] = *(const bf16x8*)(base + ((kk * 64 + fq * 16) ^ sw));
    }
    __builtin_amdgcn_s_setprio(1);
#pragma unroll
    for (int m = 0; m < 4; ++m)
#pragma unroll
      for (int n = 0; n < 4; ++n)
#pragma unroll
        for (int kk = 0; kk < 2; ++kk)
          acc[m][n] = __builtin_amdgcn_mfma_f32_16x16x32_bf16(af[m][kk], bfv[n][kk], acc[m][n], 0, 0, 0);
    __builtin_amdgcn_s_setprio(0);
  };

  const int NT = KD / 64;   // 32
  stage(0, 0);
  stage(1, 1);
  asm volatile("s_waitcnt vmcnt(6)" ::: "memory");   // tile 0 complete
  __builtin_amdgcn_sched_barrier(0);
  __builtin_amdgcn_s_barrier();
  __builtin_amdgcn_sched_barrier(0);

  int cur = 0;
#pragma unroll 1
  for (int t = 0; t < NT; ++t) {
    if (t + 2 < NT) {
      int nb = cur + 2; if (nb >= 3) nb -= 3;
      stage(t + 2, nb);                            // issue-early (T14)
    }
    compute(cur);
    if (t + 1 < NT) {
      if (t + 2 < NT) asm volatile("s_waitcnt vmcnt(6)" ::: "memory"); // t+1 done, t+2 in flight
      else            asm volatile("s_waitcnt vmcnt(0)" ::: "memory"); // tail: t+1 = last tile
      __builtin_amdgcn_sched_barrier(0);
      __builtin_amdgcn_s_barrier();
      __builtin_amdgcn_sched_barrier(0);
    }
    if (++cur == 3) cur = 0;
  }

  // epilogue: C/D frag layout col = lane&15, row = (lane>>4)*4 + j
#pragma unroll
  for (int m = 0; m < 4; ++m) {
    const size_t rb = row0 + wm * 64 + m * 16 + fq * 4;
#pragma unroll
    for (int n = 0; n < 4; ++n) {
      const int c = (int)col0 + wn * 64 + n * 16 + fr;
      const float bv = bias[c];
#pragma unroll
      for (int j = 0; j < 4; ++j)
        Cb[(rb + j) * (size_t)ldc + c] = f2bf(acc[m][n][j] + bv);
    }
  }
}

// ---------------------------------------------------------------------------
// (verified round-3 kernels below, unchanged)
// ---------------------------------------------------------------------------
template<int EPI, bool CONVA>
__global__ __launch_bounds__(256)
void gemm_bt(const void* __restrict__ Av,
             const unsigned short* __restrict__ B,
             unsigned short* __restrict__ Cb,
             float* __restrict__ Cf,
             const float* __restrict__ bias,
             const float* __restrict__ invn,
             int nNtiles, int Ncols, int ldc)
{
  __shared__ unsigned short sA[128 * 64];
  __shared__ unsigned short sB[128 * 64];
  const int bid = blockIdx.x;
  const int bm = bid / nNtiles, bn = bid % nNtiles;
  const size_t row0 = (size_t)bm * 128, col0 = (size_t)bn * 128;
  const int tid = threadIdx.x, lane = tid & 63, wv = tid >> 6;
  const char* Bb = (const char*)(B + col0 * KD);
  const int wr = (wv >> 1) * 64, wc = (wv & 1) * 64;
  const int fr = lane & 15, fq = lane >> 4;
  f32x4 acc[4][4] = {};

  const int so = wv * 1024 + lane * 16;
  const int arow = tid >> 1, ahalf = tid & 1;
  const float* Af = (const float*)Av;
  const char*  Ab = (const char*)Av;

  for (int kt = 0; kt < KD / 64; ++kt) {
    const int kbyte = kt * 128;
#pragma unroll
    for (int i = 0; i < 4; ++i) {
      const int o = i * 4096 + so;
      const int r = o >> 7, cb = o & 127;
      gload_lds16(Bb + (size_t)r * (KD * 2) + kbyte + cb, (char*)sB + o);
    }
    if (CONVA) {
      const float* ap = Af + (row0 + arow) * (size_t)KD + kt * 64 + ahalf * 32;
      float4 f[8];
#pragma unroll
      for (int j = 0; j < 8; ++j) f[j] = ((const float4*)ap)[j];
#pragma unroll
      for (int j = 0; j < 4; ++j) {
        u16x8 o;
        o[0] = f2bf(f[2*j].x);   o[1] = f2bf(f[2*j].y);
        o[2] = f2bf(f[2*j].z);   o[3] = f2bf(f[2*j].w);
        o[4] = f2bf(f[2*j+1].x); o[5] = f2bf(f[2*j+1].y);
        o[6] = f2bf(f[2*j+1].z); o[7] = f2bf(f[2*j+1].w);
        const int colb = (ahalf * 64 + j * 16) ^ ((arow & 7) << 4);
        *(u16x8*)((char*)sA + arow * 128 + colb) = o;
      }
    } else {
#pragma unroll
      for (int i = 0; i < 4; ++i) {
        const int o = i * 4096 + so;
        const int r = o >> 7, cb = o & 127;
        gload_lds16(Ab + (size_t)r * (KD * 2) + kbyte + cb, (char*)sA + o);
      }
    }
    __syncthreads();
#pragma unroll
    for (int kk = 0; kk < 2; ++kk) {
      bf16x8 af[4], bfr[4];
#pragma unroll
      for (int m = 0; m < 4; ++m) {
        const int r = wr + m * 16 + fr;
        const int colb = kk * 64 + fq * 16;
        const int off = CONVA ? (colb ^ ((r & 7) << 4)) : colb;
        af[m] = *(const bf16x8*)((const char*)sA + r * 128 + off);
      }
#pragma unroll
      for (int n = 0; n < 4; ++n)
        bfr[n] = *(const bf16x8*)((const char*)sB + (wc + n * 16 + fr) * 128 + kk * 64 + fq * 16);
#pragma unroll
      for (int m = 0; m < 4; ++m)
#pragma unroll
        for (int n = 0; n < 4; ++n)
          acc[m][n] = __builtin_amdgcn_mfma_f32_16x16x32_bf16(af[m], bfr[n], acc[m][n], 0, 0, 0);
    }
    __syncthreads();
  }

#pragma unroll
  for (int m = 0; m < 4; ++m) {
    const size_t rb = row0 + wr + m * 16 + fq * 4;
#pragma unroll
    for (int n = 0; n < 4; ++n) {
      const int c = (int)col0 + wc + n * 16 + fr;
      if (EPI == 1 && c >= Ncols) continue;
      const float bv = (EPI == 0 || EPI == 1) ? bias[c] : 0.f;
#pragma unroll
      for (int j = 0; j < 4; ++j) {
        const size_t r = rb + j;
        const float v = acc[m][n][j];
        if (EPI == 0)      Cb[r * (size_t)ldc + c] = f2bf(v + bv);
        else if (EPI == 1) Cf[r * (size_t)ldc + c] = v + bv;
        else               Cf[r * (size_t)ldc + c] = v * invn[r];
      }
    }
  }
}

__global__ __launch_bounds__(256)
void prep_x(const float* __restrict__ x, unsigned short* __restrict__ xbf,
            float* __restrict__ invn)
{
  const int n = blockIdx.x, tid = threadIdx.x;
  const float4* row = (const float4*)(x + (size_t)n * KD);
  float4 a = row[tid * 2], b = row[tid * 2 + 1];
  float ss = a.x * a.x + a.y * a.y + a.z * a.z + a.w * a.w
           + b.x * b.x + b.y * b.y + b.z * b.z + b.w * b.w;
#pragma unroll
  for (int off = 32; off > 0; off >>= 1) ss += __shfl_down(ss, off);
  __shared__ float red[4];
  if ((tid & 63) == 0) red[tid >> 6] = ss;
  __syncthreads();
  if (tid == 0) {
    const float tot = red[0] + red[1] + red[2] + red[3];
    invn[n] = 1.f / fmaxf(sqrtf(tot), 1e-8f);
  }
  u16x8 o;
  o[0] = f2bf(a.x); o[1] = f2bf(a.y); o[2] = f2bf(a.z); o[3] = f2bf(a.w);
  o[4] = f2bf(b.x); o[5] = f2bf(b.y); o[6] = f2bf(b.z); o[7] = f2bf(b.w);
  *(u16x8*)(xbf + (size_t)n * KD + (size_t)tid * 8) = o;
}

__global__ __launch_bounds__(256)
void row_norms(const float* __restrict__ x, float* __restrict__ invn)
{
  const int n = blockIdx.x, tid = threadIdx.x;
  const float4* row = (const float4*)(x + (size_t)n * KD);
  float4 a = row[tid * 2], b = row[tid * 2 + 1];
  float ss = a.x * a.x + a.y * a.y + a.z * a.z + a.w * a.w
           + b.x * b.x + b.y * b.y + b.z * b.z + b.w * b.w;
#pragma unroll
  for (int off = 32; off > 0; off >>= 1) ss += __shfl_down(ss, off);
  __shared__ float red[4];
  if ((tid & 63) == 0) red[tid >> 6] = ss;
  __syncthreads();
  if (tid == 0) {
    const float tot = red[0] + red[1] + red[2] + red[3];
    invn[n] = 1.f / fmaxf(sqrtf(tot), 1e-8f);
  }
}

__global__ __launch_bounds__(256)
void cvt_w1(const float* __restrict__ in, unsigned short* __restrict__ out)
{
  const size_t i = (size_t)blockIdx.x * 256 + threadIdx.x;
  const float4* p = (const float4*)(in + i * 8);
  float4 a = p[0], b = p[1];
  u16x8 o;
  o[0] = f2bf(a.x); o[1] = f2bf(a.y); o[2] = f2bf(a.z); o[3] = f2bf(a.w);
  o[4] = f2bf(b.x); o[5] = f2bf(b.y); o[6] = f2bf(b.z); o[7] = f2bf(b.w);
  *(u16x8*)(out + i * 8) = o;
}

__global__ __launch_bounds__(256)
void prep_rows(const float* __restrict__ reps, const float* __restrict__ negrep,
               const float* __restrict__ bbox,
               unsigned short* __restrict__ RN, unsigned short* __restrict__ W2)
{
  const int r = blockIdx.x, tid = threadIdx.x;
  const u16x8 z = {0, 0, 0, 0, 0, 0, 0, 0};
  if (r < 256) {
    unsigned short* dst = RN + (size_t)r * KD;
    if (r >= 240) { *(u16x8*)(dst + (size_t)tid * 8) = z; return; }
    const float* src = (r < 60) ? reps + (size_t)r * KD
                                : negrep + (size_t)(r - 60) * KD;
    const float4* p = (const float4*)src;
    float4 a = p[tid * 2], b = p[tid * 2 + 1];
    float ss = a.x * a.x + a.y * a.y + a.z * a.z + a.w * a.w
             + b.x * b.x + b.y * b.y + b.z * b.z + b.w * b.w;
#pragma unroll
    for (int off = 32; off > 0; off >>= 1) ss += __shfl_down(ss, off);
    __shared__ float red[4];
    if ((tid & 63) == 0) red[tid >> 6] = ss;
    __syncthreads();
    const float iv = 1.f / fmaxf(sqrtf(red[0] + red[1] + red[2] + red[3]), 1e-8f);
    u16x8 o;
    o[0] = f2bf(a.x * iv); o[1] = f2bf(a.y * iv); o[2] = f2bf(a.z * iv); o[3] = f2bf(a.w * iv);
    o[4] = f2bf(b.x * iv); o[5] = f2bf(b.y * iv); o[6] = f2bf(b.z * iv); o[7] = f2bf(b.w * iv);
    *(u16x8*)(dst + (size_t)tid * 8) = o;
  } else {
    const int rr = r - 256;
    unsigned short* dst = W2 + (size_t)rr * KD;
    if (rr >= 240) { *(u16x8*)(dst + (size_t)tid * 8) = z; return; }
    const float4* p = (const float4*)(bbox + (size_t)rr * KD);
    float4 a = p[tid * 2], b = p[tid * 2 + 1];
    u16x8 o;
    o[0] = f2bf(a.x); o[1] = f2bf(a.y); o[2] = f2bf(a.z); o[3] = f2bf(a.w);
    o[4] = f2bf(b.x); o[5] = f2bf(b.y); o[6] = f2bf(b.z); o[7] = f2bf(b.w);
    *(u16x8*)(dst + (size_t)tid * 8) = o;
  }
}

__global__ __launch_bounds__(64)
void post(const float* __restrict__ S, float* __restrict__ out)
{
  const int n = blockIdx.x, c = threadIdx.x;
  const float* s = S + (size_t)n * 256;
  float* scores = out;
  float* cosv   = out + OFF_COS;
  float* negc   = out + OFF_NEGC;
  float* negs   = out + OFF_NEGS;
  if (c < 60) {
    const float cs = s[c];
    cosv[(size_t)n * 60 + c]   = cs;
    scores[(size_t)n * 61 + c] = expf(-(1.f - cs) * 20.f);
    const float m3 = fmaxf(s[60 + 3 * c], fmaxf(s[61 + 3 * c], s[62 + 3 * c]));
    negc[(size_t)n * 60 + c] = m3;
    negs[(size_t)n * 60 + c] = expf(-(1.f - m3) * 20.f);
  } else if (c == 60) {
    scores[(size_t)n * 61 + 60] = -100000.0f;
  }
}

extern "C" void kernel_launch(void* const* d_in, const int* in_sizes, int n_in,
                              void* d_out, int out_size, void* d_ws, size_t ws_size,
                              hipStream_t stream)
{
  const float* x      = (const float*)d_in[0];
  const float* reps   = (const float*)d_in[1];
  const float* negrep = (const float*)d_in[2];
  const float* w1     = (const float*)d_in[3];
  const float* b1     = (const float*)d_in[4];
  const float* w2     = (const float*)d_in[5];
  const float* b2     = (const float*)d_in[6];
  float* out = (float*)d_out;

  char* w = (char*)d_ws;
  unsigned short* Hbf  = (unsigned short*)(w);             // 64 MiB
  unsigned short* W1bf = (unsigned short*)(w + 67108864);  // 8 MiB
  unsigned short* W2bf = (unsigned short*)(w + 75497472);  // 1 MiB
  unsigned short* RNbf = (unsigned short*)(w + 76546048);  // 1 MiB
  float*          invn = (float*)(w + 77594624);           // 64 KiB
  unsigned short* xbf  = (unsigned short*)(w + 77660160);  // 64 MiB (end 144769024)
  float*          S    = (float*)w;  // aliases Hbf; written only after gemm<1> consumed Hbf

  const bool big = ws_size >= 144769024ull;

  cvt_w1<<<2048, 256, 0, stream>>>(w1, W1bf);
  prep_rows<<<512, 256, 0, stream>>>(reps, negrep, w2, RNbf, W2bf);

  if (big) {
    prep_x<<<NROWS, 256, 0, stream>>>(x, xbf, invn);
    // H = x @ W1^T + b1 (bf16 internal) — new 256x128 counted-vmcnt kernel
    gemm256<<<64 * 16, 512, 0, stream>>>(xbf, W1bf, Hbf, b1, 16, 2048);
    // deltas = H @ bbox^T + b2 -> out (f32)
    gemm_bt<1, false><<<128 * 2, 256, 0, stream>>>(Hbf, W2bf, nullptr, out + OFF_DELTAS, b2, nullptr, 2, 240, 240);
    // S = (x @ [rn;nrn]^T) * invn -> ws (f32)
    gemm_bt<2, false><<<128 * 2, 256, 0, stream>>>(xbf, RNbf, nullptr, S, nullptr, invn, 2, 256, 256);
  } else {
    row_norms<<<NROWS, 256, 0, stream>>>(x, invn);
    gemm_bt<0, true><<<128 * 16, 256, 0, stream>>>(x, W1bf, Hbf, nullptr, b1, nullptr, 16, 2048, 2048);
    gemm_bt<1, false><<<128 * 2, 256, 0, stream>>>(Hbf, W2bf, nullptr, out + OFF_DELTAS, b2, nullptr, 2, 240, 240);
    gemm_bt<2, true><<<128 * 2, 256, 0, stream>>>(x, RNbf, nullptr, S, nullptr, invn, 2, 256, 256);
  }
  post<<<NROWS, 64, 0, stream>>>(S, out);
}

// Round 5
// 322.007 us; speedup vs baseline: 1.6038x; 1.4518x over previous
//
#include <hip/hip_runtime.h>
#include <stdint.h>

#define KD 2048
#define NROWS 16384

typedef float f32x4 __attribute__((ext_vector_type(4)));
typedef __bf16 bf16x8 __attribute__((ext_vector_type(8)));
typedef unsigned short u16x8 __attribute__((ext_vector_type(8)));
typedef unsigned short u16x4 __attribute__((ext_vector_type(4)));

// out layout (f32 elements): scores[N][61] | deltas[N][240] | cos[N][60] | negcos[N][60] | negscr[N][60]
#define OFF_DELTAS 999424
#define OFF_COS    4931584
#define OFF_NEGC   5914624
#define OFF_NEGS   6897664

// round-to-nearest-even f32 -> bf16 bits
__device__ inline unsigned short f2bf(float f) {
  union { float f; unsigned u; } v; v.f = f;
  unsigned u = v.u;
  return (unsigned short)((u + 0x7FFFu + ((u >> 16) & 1u)) >> 16);
}

__device__ inline void gload_lds16(const void* g, void* l) {
  __builtin_amdgcn_global_load_lds(
      (const __attribute__((address_space(1))) void*)g,
      (__attribute__((address_space(3))) void*)l,
      16, 0, 0);
}

// ===========================================================================
// gemm256: one pass over x computes BOTH the cos/neg dot block and deltas.
//   A = xbf [16384 x 2048] bf16, B = Big [512 x 2048] bf16
//   Big rows 0..255  = [rn(60); nrn(180); 0(16)]  -> S  = dot * invn[row]
//   Big rows 256..511 = [Wfold(240); 0(16)]       -> deltas = dot + bfold[c]
// BM=256 BN=128 BK=64, 8 waves (4Mx2N), 512 thr, 3-buf rotation, vmcnt(6).
// LDS XOR-swizzle byte^((row&7)<<4) on pre-swizzled global source + ds_read.
// ===========================================================================
__global__ __launch_bounds__(512, 2)
void gemm256(const unsigned short* __restrict__ A,
             const unsigned short* __restrict__ B,
             float* __restrict__ Sf,
             float* __restrict__ Df,
             const float* __restrict__ invn,
             const float* __restrict__ bfold,
             int nNtiles)
{
  __shared__ __align__(16) char lds[3 * 49152];   // 144 KiB
  const int bid = blockIdx.x;
  const int bm = bid / nNtiles, bn = bid % nNtiles;
  const size_t row0 = (size_t)bm * 256, col0 = (size_t)bn * 128;
  const int tid = threadIdx.x, lane = tid & 63, wv = tid >> 6;
  const int wm = wv >> 1, wn = wv & 1;
  const int fr = lane & 15, fq = lane >> 4;
  const char* Ab = (const char*)(A + row0 * KD);
  const char* Bb = (const char*)(B + col0 * KD);
  f32x4 acc[4][4] = {};

  int aoff[4], aG[4], boff[2], bG[2];
#pragma unroll
  for (int s = 0; s < 4; ++s) {
    const int o = (tid + s * 512) * 16;
    const int r = o >> 7;
    aoff[s] = o;
    aG[s] = r * (KD * 2) + ((o & 127) ^ ((r & 7) << 4));
  }
#pragma unroll
  for (int s = 0; s < 2; ++s) {
    const int o = (tid + s * 512) * 16;
    const int r = o >> 7;
    boff[s] = o;
    bG[s] = r * (KD * 2) + ((o & 127) ^ ((r & 7) << 4));
  }

  auto stage = [&](int kt, int b) {
    char* bufA = lds + b * 49152;
    char* bufB = bufA + 32768;
    const int kby = kt * 128;
#pragma unroll
    for (int s = 0; s < 4; ++s)
      gload_lds16(Ab + (size_t)(aG[s] + kby), bufA + aoff[s]);
#pragma unroll
    for (int s = 0; s < 2; ++s)
      gload_lds16(Bb + (size_t)(bG[s] + kby), bufB + boff[s]);
  };

  const int sw = (fr & 7) << 4;

  auto compute = [&](int b) {
    const char* bufA = lds + b * 49152;
    const char* bufB = bufA + 32768;
    bf16x8 af[4][2], bfv[4][2];
#pragma unroll
    for (int m = 0; m < 4; ++m) {
      const char* base = bufA + (wm * 64 + m * 16 + fr) * 128;
#pragma unroll
      for (int kk = 0; kk < 2; ++kk)
        af[m][kk] = *(const bf16x8*)(base + ((kk * 64 + fq * 16) ^ sw));
    }
#pragma unroll
    for (int n = 0; n < 4; ++n) {
      const char* base = bufB + (wn * 64 + n * 16 + fr) * 128;
#pragma unroll
      for (int kk = 0; kk < 2; ++kk)
        bfv[n][kk] = *(const bf16x8*)(base + ((kk * 64 + fq * 16) ^ sw));
    }
    __builtin_amdgcn_s_setprio(1);
#pragma unroll
    for (int m = 0; m < 4; ++m)
#pragma unroll
      for (int n = 0; n < 4; ++n)
#pragma unroll
        for (int kk = 0; kk < 2; ++kk)
          acc[m][n] = __builtin_amdgcn_mfma_f32_16x16x32_bf16(af[m][kk], bfv[n][kk], acc[m][n], 0, 0, 0);
    __builtin_amdgcn_s_setprio(0);
  };

  const int NT = KD / 64;   // 32
  stage(0, 0);
  stage(1, 1);
  asm volatile("s_waitcnt vmcnt(6)" ::: "memory");
  __builtin_amdgcn_sched_barrier(0);
  __builtin_amdgcn_s_barrier();
  __builtin_amdgcn_sched_barrier(0);

  int cur = 0;
#pragma unroll 1
  for (int t = 0; t < NT; ++t) {
    if (t + 2 < NT) {
      int nb = cur + 2; if (nb >= 3) nb -= 3;
      stage(t + 2, nb);
    }
    compute(cur);
    if (t + 1 < NT) {
      if (t + 2 < NT) asm volatile("s_waitcnt vmcnt(6)" ::: "memory");
      else            asm volatile("s_waitcnt vmcnt(0)" ::: "memory");
      __builtin_amdgcn_sched_barrier(0);
      __builtin_amdgcn_s_barrier();
      __builtin_amdgcn_sched_barrier(0);
    }
    if (++cur == 3) cur = 0;
  }

  // epilogue: C/D frag col = lane&15, row = (lane>>4)*4 + j
  // bn 0,1 -> S (cols 0..255); bn 2,3 -> deltas (cols 256..495 -> 0..239)
#pragma unroll
  for (int m = 0; m < 4; ++m) {
    const size_t rb = row0 + wm * 64 + m * 16 + fq * 4;
#pragma unroll
    for (int n = 0; n < 4; ++n) {
      const int c = (int)col0 + wn * 64 + n * 16 + fr;
      if (bn < 2) {
#pragma unroll
        for (int j = 0; j < 4; ++j) {
          const size_t r = rb + j;
          Sf[r * 256 + c] = acc[m][n][j] * invn[r];
        }
      } else {
        const int c2 = c - 256;
        if (c2 < 240) {
          const float bv = bfold[c2];
#pragma unroll
          for (int j = 0; j < 4; ++j)
            Df[(rb + j) * 240 + c2] = acc[m][n][j] + bv;
        }
      }
    }
  }
}

// ---------------------------------------------------------------------------
// fold GEMM (verified m97 structure): Wfold = W2 @ W1  as A@B^T with B = W1^T
// A = W2bf [256 x 2048] bf16 (rows 240..255 zero), B = W1T [2048 x 2048] bf16
// EPI3: Cb = bf16(acc), no bias.
// ---------------------------------------------------------------------------
template<int EPI>
__global__ __launch_bounds__(256)
void gemm_bt(const unsigned short* __restrict__ A,
             const unsigned short* __restrict__ B,
             unsigned short* __restrict__ Cb,
             int nNtiles, int ldc)
{
  __shared__ unsigned short sA[128 * 64];
  __shared__ unsigned short sB[128 * 64];
  const int bid = blockIdx.x;
  const int bm = bid / nNtiles, bn = bid % nNtiles;
  const size_t row0 = (size_t)bm * 128, col0 = (size_t)bn * 128;
  const int tid = threadIdx.x, lane = tid & 63, wv = tid >> 6;
  const char* Ab = (const char*)(A + row0 * KD);
  const char* Bb = (const char*)(B + col0 * KD);
  const int wr = (wv >> 1) * 64, wc = (wv & 1) * 64;
  const int fr = lane & 15, fq = lane >> 4;
  f32x4 acc[4][4] = {};
  const int so = wv * 1024 + lane * 16;

  for (int kt = 0; kt < KD / 64; ++kt) {
    const int kbyte = kt * 128;
#pragma unroll
    for (int i = 0; i < 4; ++i) {
      const int o = i * 4096 + so;
      const int r = o >> 7, cb = o & 127;
      gload_lds16(Ab + (size_t)r * (KD * 2) + kbyte + cb, (char*)sA + o);
      gload_lds16(Bb + (size_t)r * (KD * 2) + kbyte + cb, (char*)sB + o);
    }
    __syncthreads();
#pragma unroll
    for (int kk = 0; kk < 2; ++kk) {
      bf16x8 af[4], bfr[4];
#pragma unroll
      for (int m = 0; m < 4; ++m)
        af[m] = *(const bf16x8*)((const char*)sA + (wr + m * 16 + fr) * 128 + kk * 64 + fq * 16);
#pragma unroll
      for (int n = 0; n < 4; ++n)
        bfr[n] = *(const bf16x8*)((const char*)sB + (wc + n * 16 + fr) * 128 + kk * 64 + fq * 16);
#pragma unroll
      for (int m = 0; m < 4; ++m)
#pragma unroll
        for (int n = 0; n < 4; ++n)
          acc[m][n] = __builtin_amdgcn_mfma_f32_16x16x32_bf16(af[m], bfr[n], acc[m][n], 0, 0, 0);
    }
    __syncthreads();
  }

#pragma unroll
  for (int m = 0; m < 4; ++m) {
    const size_t rb = row0 + wr + m * 16 + fq * 4;
#pragma unroll
    for (int n = 0; n < 4; ++n) {
      const int c = (int)col0 + wc + n * 16 + fr;
#pragma unroll
      for (int j = 0; j < 4; ++j)
        Cb[(rb + j) * (size_t)ldc + c] = f2bf(acc[m][n][j]);
    }
  }
}

// x (f32) -> bf16 copy + per-row 1/max(||x||,eps)
__global__ __launch_bounds__(256)
void prep_x(const float* __restrict__ x, unsigned short* __restrict__ xbf,
            float* __restrict__ invn)
{
  const int n = blockIdx.x, tid = threadIdx.x;
  const float4* row = (const float4*)(x + (size_t)n * KD);
  float4 a = row[tid * 2], b = row[tid * 2 + 1];
  float ss = a.x * a.x + a.y * a.y + a.z * a.z + a.w * a.w
           + b.x * b.x + b.y * b.y + b.z * b.z + b.w * b.w;
#pragma unroll
  for (int off = 32; off > 0; off >>= 1) ss += __shfl_down(ss, off);
  __shared__ float red[4];
  if ((tid & 63) == 0) red[tid >> 6] = ss;
  __syncthreads();
  if (tid == 0) {
    const float tot = red[0] + red[1] + red[2] + red[3];
    invn[n] = 1.f / fmaxf(sqrtf(tot), 1e-8f);
  }
  u16x8 o;
  o[0] = f2bf(a.x); o[1] = f2bf(a.y); o[2] = f2bf(a.z); o[3] = f2bf(a.w);
  o[4] = f2bf(b.x); o[5] = f2bf(b.y); o[6] = f2bf(b.z); o[7] = f2bf(b.w);
  *(u16x8*)(xbf + (size_t)n * KD + (size_t)tid * 8) = o;
}

// W1T[j][i] = w1[i][j], bf16 out. 64x64 tiles, padded LDS.
__global__ __launch_bounds__(256)
void trans_w1(const float* __restrict__ w1, unsigned short* __restrict__ w1t)
{
  __shared__ float t[64][65];
  const int i0 = (blockIdx.x & 31) * 64;   // w1 row block
  const int j0 = (blockIdx.x >> 5) * 64;   // w1 col block
  const int tid = threadIdx.x;
  const int r = tid >> 4, c4 = tid & 15;
#pragma unroll
  for (int rr = 0; rr < 4; ++rr) {
    const int row = r + rr * 16;
    const float4 v = *(const float4*)(w1 + (size_t)(i0 + row) * KD + j0 + c4 * 4);
    t[row][c4 * 4 + 0] = v.x; t[row][c4 * 4 + 1] = v.y;
    t[row][c4 * 4 + 2] = v.z; t[row][c4 * 4 + 3] = v.w;
  }
  __syncthreads();
#pragma unroll
  for (int rr = 0; rr < 4; ++rr) {
    const int jrow = r + rr * 16;
    u16x4 o;
    o[0] = f2bf(t[c4 * 4 + 0][jrow]); o[1] = f2bf(t[c4 * 4 + 1][jrow]);
    o[2] = f2bf(t[c4 * 4 + 2][jrow]); o[3] = f2bf(t[c4 * 4 + 3][jrow]);
    *(u16x4*)(w1t + (size_t)(j0 + jrow) * KD + i0 + c4 * 4) = o;
  }
}

// bfold[c] = dot(w2[c], b1) + b2[c]   (f32, exact path)
__global__ __launch_bounds__(256)
void bfold_k(const float* __restrict__ w2, const float* __restrict__ b1,
             const float* __restrict__ b2, float* __restrict__ bf)
{
  const int c = blockIdx.x, tid = threadIdx.x;
  const float4* row = (const float4*)(w2 + (size_t)c * KD);
  const float4* bb  = (const float4*)b1;
  float4 a = row[tid * 2], b = row[tid * 2 + 1];
  float4 p = bb[tid * 2],  q = bb[tid * 2 + 1];
  float ss = a.x * p.x + a.y * p.y + a.z * p.z + a.w * p.w
           + b.x * q.x + b.y * q.y + b.z * q.z + b.w * q.w;
#pragma unroll
  for (int off = 32; off > 0; off >>= 1) ss += __shfl_down(ss, off);
  __shared__ float red[4];
  if ((tid & 63) == 0) red[tid >> 6] = ss;
  __syncthreads();
  if (tid == 0) bf[c] = red[0] + red[1] + red[2] + red[3] + b2[c];
}

// blocks 0..255: Big rows 0..255 (rn/nrn normalized, pad zero)
// blocks 256..511: W2bf rows (bbox_w bf16, pad zero)
__global__ __launch_bounds__(256)
void prep_rows(const float* __restrict__ reps, const float* __restrict__ negrep,
               const float* __restrict__ bbox,
               unsigned short* __restrict__ Big, unsigned short* __restrict__ W2)
{
  const int r = blockIdx.x, tid = threadIdx.x;
  const u16x8 z = {0, 0, 0, 0, 0, 0, 0, 0};
  if (r < 256) {
    unsigned short* dst = Big + (size_t)r * KD;
    if (r >= 240) { *(u16x8*)(dst + (size_t)tid * 8) = z; return; }
    const float* src = (r < 60) ? reps + (size_t)r * KD
                                : negrep + (size_t)(r - 60) * KD;
    const float4* p = (const float4*)src;
    float4 a = p[tid * 2], b = p[tid * 2 + 1];
    float ss = a.x * a.x + a.y * a.y + a.z * a.z + a.w * a.w
             + b.x * b.x + b.y * b.y + b.z * b.z + b.w * b.w;
#pragma unroll
    for (int off = 32; off > 0; off >>= 1) ss += __shfl_down(ss, off);
    __shared__ float red[4];
    if ((tid & 63) == 0) red[tid >> 6] = ss;
    __syncthreads();
    const float iv = 1.f / fmaxf(sqrtf(red[0] + red[1] + red[2] + red[3]), 1e-8f);
    u16x8 o;
    o[0] = f2bf(a.x * iv); o[1] = f2bf(a.y * iv); o[2] = f2bf(a.z * iv); o[3] = f2bf(a.w * iv);
    o[4] = f2bf(b.x * iv); o[5] = f2bf(b.y * iv); o[6] = f2bf(b.z * iv); o[7] = f2bf(b.w * iv);
    *(u16x8*)(dst + (size_t)tid * 8) = o;
  } else {
    const int rr = r - 256;
    unsigned short* dst = W2 + (size_t)rr * KD;
    if (rr >= 240) { *(u16x8*)(dst + (size_t)tid * 8) = z; return; }
    const float4* p = (const float4*)(bbox + (size_t)rr * KD);
    float4 a = p[tid * 2], b = p[tid * 2 + 1];
    u16x8 o;
    o[0] = f2bf(a.x); o[1] = f2bf(a.y); o[2] = f2bf(a.z); o[3] = f2bf(a.w);
    o[4] = f2bf(b.x); o[5] = f2bf(b.y); o[6] = f2bf(b.z); o[7] = f2bf(b.w);
    *(u16x8*)(dst + (size_t)tid * 8) = o;
  }
}

// S[n][0..59] = cos_sim (already *invnorm), S[n][60+3c+m] = neg dots
__global__ __launch_bounds__(64)
void post(const float* __restrict__ S, float* __restrict__ out)
{
  const int n = blockIdx.x, c = threadIdx.x;
  const float* s = S + (size_t)n * 256;
  float* scores = out;
  float* cosv   = out + OFF_COS;
  float* negc   = out + OFF_NEGC;
  float* negs   = out + OFF_NEGS;
  if (c < 60) {
    const float cs = s[c];
    cosv[(size_t)n * 60 + c]   = cs;
    scores[(size_t)n * 61 + c] = expf(-(1.f - cs) * 20.f);
    const float m3 = fmaxf(s[60 + 3 * c], fmaxf(s[61 + 3 * c], s[62 + 3 * c]));
    negc[(size_t)n * 60 + c] = m3;
    negs[(size_t)n * 60 + c] = expf(-(1.f - m3) * 20.f);
  } else if (c == 60) {
    scores[(size_t)n * 61 + 60] = -100000.0f;
  }
}

extern "C" void kernel_launch(void* const* d_in, const int* in_sizes, int n_in,
                              void* d_out, int out_size, void* d_ws, size_t ws_size,
                              hipStream_t stream)
{
  const float* x      = (const float*)d_in[0];
  const float* reps   = (const float*)d_in[1];
  const float* negrep = (const float*)d_in[2];
  const float* w1     = (const float*)d_in[3];
  const float* b1     = (const float*)d_in[4];
  const float* w2     = (const float*)d_in[5];
  const float* b2     = (const float*)d_in[6];
  float* out = (float*)d_out;

  // ws carve — 95.5 MiB total (ws_size >= 144.8 MiB confirmed in r4)
  char* w = (char*)d_ws;
  float*          S    = (float*)(w);                      // 16 MiB  [0, 16777216)
  unsigned short* Big  = (unsigned short*)(w + 16777216);  // 2 MiB   (512 x 2048 bf16)
  unsigned short* W1T  = (unsigned short*)(w + 18874368);  // 8 MiB
  unsigned short* W2bf = (unsigned short*)(w + 27262976);  // 1 MiB
  float*          invn = (float*)(w + 28311552);           // 64 KiB
  float*          bfold= (float*)(w + 28377088);           // 1 KiB
  unsigned short* xbf  = (unsigned short*)(w + 28378112);  // 64 MiB (end 95486976)

  prep_x   <<<NROWS, 256, 0, stream>>>(x, xbf, invn);
  trans_w1 <<<1024, 256, 0, stream>>>(w1, W1T);
  prep_rows<<<512, 256, 0, stream>>>(reps, negrep, w2, Big, W2bf);
  bfold_k  <<<240, 256, 0, stream>>>(w2, b1, b2, bfold);

  // Wfold = W2 @ W1  -> Big rows 256..511 (bf16)
  gemm_bt<3><<<2 * 16, 256, 0, stream>>>(W2bf, W1T, Big + 256 * (size_t)KD, 16, 2048);

  // S (cols 0..255) + deltas (cols 256..495) in one pass over x
  gemm256<<<64 * 4, 512, 0, stream>>>(xbf, Big, S, out + OFF_DELTAS, invn, bfold, 4);

  post<<<NROWS, 64, 0, stream>>>(S, out);
}

// Round 7
// 285.209 us; speedup vs baseline: 1.8107x; 1.1290x over previous
//
#include <hip/hip_runtime.h>
#include <stdint.h>

#define KD 2048
#define NROWS 16384

typedef float f32x4 __attribute__((ext_vector_type(4)));
typedef __bf16 bf16x8 __attribute__((ext_vector_type(8)));
typedef unsigned short u16x8 __attribute__((ext_vector_type(8)));
typedef unsigned short u16x4 __attribute__((ext_vector_type(4)));

// out layout (f32 elements): scores[N][61] | deltas[N][240] | cos[N][60] | negcos[N][60] | negscr[N][60]
#define OFF_DELTAS 999424
#define OFF_COS    4931584
#define OFF_NEGC   5914624
#define OFF_NEGS   6897664

__device__ inline unsigned short f2bf(float f) {
  union { float f; unsigned u; } v; v.f = f;
  unsigned u = v.u;
  return (unsigned short)((u + 0x7FFFu + ((u >> 16) & 1u)) >> 16);
}

__device__ inline void gload_lds16(const void* g, void* l) {
  __builtin_amdgcn_global_load_lds(
      (const __attribute__((address_space(1))) void*)g,
      (__attribute__((address_space(3))) void*)l,
      16, 0, 0);
}

// ===========================================================================
// gemm256: C[16384 x 512] = xbf @ Big^T, BM=128 BN=256 BK=64, 8 waves (2Mx4N),
// 512 thr, 3-buf rotation (48KB = A16+B32), counted vmcnt(6).
// bn=0 (Big rows 0..255 = rn/nrn): S-tile staged in (dead) K-loop LDS, then
//   scores/cos/negcos/negscores written FINAL (post fused).
// bn=1 (Big rows 256..511 = Wfold): deltas written final.
// ===========================================================================
__global__ __launch_bounds__(512, 2)
void gemm256(const unsigned short* __restrict__ A,
             const unsigned short* __restrict__ B,
             float* __restrict__ out,
             const float* __restrict__ invn,
             const float* __restrict__ bfold)
{
  __shared__ __align__(16) char lds[3 * 49152];   // 144 KiB
  const int bid = blockIdx.x;
  const int bm = bid >> 1, bn = bid & 1;
  const size_t row0 = (size_t)bm * 128, col0 = (size_t)bn * 256;
  const int tid = threadIdx.x, lane = tid & 63, wv = tid >> 6;
  const int wm = wv >> 2, wn = wv & 3;            // 2M x 4N wave grid (64x64 each)
  const int fr = lane & 15, fq = lane >> 4;
  const char* Ab = (const char*)(A + row0 * KD);
  const char* Bb = (const char*)(B + col0 * KD);
  f32x4 acc[4][4] = {};

  // staging: A 16KB (2 chunks/thr), B 32KB (4 chunks/thr); global col
  // pre-swizzled so linear gload_lds writes build the swizzled LDS image
  int aoff[2], aG[2], boff[4], bG[4];
#pragma unroll
  for (int s = 0; s < 2; ++s) {
    const int o = (tid + s * 512) * 16;
    const int r = o >> 7;
    aoff[s] = o;
    aG[s] = r * (KD * 2) + ((o & 127) ^ ((r & 7) << 4));
  }
#pragma unroll
  for (int s = 0; s < 4; ++s) {
    const int o = (tid + s * 512) * 16;
    const int r = o >> 7;
    boff[s] = o;
    bG[s] = r * (KD * 2) + ((o & 127) ^ ((r & 7) << 4));
  }

  auto stage = [&](int kt, int b) {
    char* bufA = lds + b * 49152;
    char* bufB = bufA + 16384;
    const int kby = kt * 128;
#pragma unroll
    for (int s = 0; s < 2; ++s)
      gload_lds16(Ab + (size_t)(aG[s] + kby), bufA + aoff[s]);
#pragma unroll
    for (int s = 0; s < 4; ++s)
      gload_lds16(Bb + (size_t)(bG[s] + kby), bufB + boff[s]);
  };

  const int sw = (fr & 7) << 4;

  auto compute = [&](int b) {
    const char* bufA = lds + b * 49152;
    const char* bufB = bufA + 16384;
    bf16x8 af[4][2], bfv[4][2];
#pragma unroll
    for (int m = 0; m < 4; ++m) {
      const char* base = bufA + (wm * 64 + m * 16 + fr) * 128;
#pragma unroll
      for (int kk = 0; kk < 2; ++kk)
        af[m][kk] = *(const bf16x8*)(base + ((kk * 64 + fq * 16) ^ sw));
    }
#pragma unroll
    for (int n = 0; n < 4; ++n) {
      const char* base = bufB + (wn * 64 + n * 16 + fr) * 128;
#pragma unroll
      for (int kk = 0; kk < 2; ++kk)
        bfv[n][kk] = *(const bf16x8*)(base + ((kk * 64 + fq * 16) ^ sw));
    }
    __builtin_amdgcn_s_setprio(1);
#pragma unroll
    for (int m = 0; m < 4; ++m)
#pragma unroll
      for (int n = 0; n < 4; ++n)
#pragma unroll
        for (int kk = 0; kk < 2; ++kk)
          acc[m][n] = __builtin_amdgcn_mfma_f32_16x16x32_bf16(af[m][kk], bfv[n][kk], acc[m][n], 0, 0, 0);
    __builtin_amdgcn_s_setprio(0);
  };

  const int NT = KD / 64;   // 32
  stage(0, 0);
  stage(1, 1);
  asm volatile("s_waitcnt vmcnt(6)" ::: "memory");
  __builtin_amdgcn_sched_barrier(0);
  __builtin_amdgcn_s_barrier();
  __builtin_amdgcn_sched_barrier(0);

  int cur = 0;
#pragma unroll 1
  for (int t = 0; t < NT; ++t) {
    if (t + 2 < NT) {
      int nb = cur + 2; if (nb >= 3) nb -= 3;
      stage(t + 2, nb);
    }
    compute(cur);
    if (t + 1 < NT) {
      if (t + 2 < NT) asm volatile("s_waitcnt vmcnt(6)" ::: "memory");
      else            asm volatile("s_waitcnt vmcnt(0)" ::: "memory");
      __builtin_amdgcn_sched_barrier(0);
      __builtin_amdgcn_s_barrier();
      __builtin_amdgcn_sched_barrier(0);
    }
    if (++cur == 3) cur = 0;
  }

  __syncthreads();   // all waves done reading K-loop LDS
  // C/D frag: col = lane&15 (fr), row = fq*4 + j
  if (bn == 1) {
    // deltas = dot + bfold, cols (Big rows 256..495) -> classes 0..239
    float* Df = out + OFF_DELTAS;
#pragma unroll
    for (int n = 0; n < 4; ++n) {
      const int c = wn * 64 + n * 16 + fr;
      if (c < 240) {
        const float bv = bfold[c];
#pragma unroll
        for (int m = 0; m < 4; ++m) {
          const size_t rb = row0 + wm * 64 + m * 16 + fq * 4;
#pragma unroll
          for (int j = 0; j < 4; ++j)
            Df[(rb + j) * 240 + c] = acc[m][n][j] + bv;
        }
      }
    }
  } else {
    // stage S-tile [128][256] f32 in the dead K-loop LDS
    float* sT = (float*)lds;
#pragma unroll
    for (int m = 0; m < 4; ++m) {
      const int rl = wm * 64 + m * 16 + fq * 4;   // local row base
#pragma unroll
      for (int j = 0; j < 4; ++j) {
        const float iv = invn[row0 + rl + j];
#pragma unroll
        for (int n = 0; n < 4; ++n)
          sT[(rl + j) * 256 + wn * 64 + n * 16 + fr] = acc[m][n][j] * iv;
      }
    }
    __syncthreads();
    // final outputs, coalesced (constant-divisor magic div)
    float* scores = out + row0 * 61;
    float* cosv   = out + OFF_COS  + row0 * 60;
    float* negc   = out + OFF_NEGC + row0 * 60;
    float* negs   = out + OFF_NEGS + row0 * 60;
    for (int i = tid; i < 128 * 61; i += 512) {
      const int r = i / 61, c = i - r * 61;
      scores[i] = (c == 60) ? -100000.0f : expf(-(1.f - sT[r * 256 + c]) * 20.f);
    }
    for (int i = tid; i < 128 * 60; i += 512) {
      const int r = i / 60, c = i - r * 60;
      const float* sr = sT + r * 256;
      cosv[i] = sr[c];
      const float m3 = fmaxf(sr[60 + 3 * c], fmaxf(sr[61 + 3 * c], sr[62 + 3 * c]));
      negc[i] = m3;
      negs[i] = expf(-(1.f - m3) * 20.f);
    }
  }
}

// ---------------------------------------------------------------------------
// fold_split: partial Wfold = W2 @ W1 over a K-chunk (4 x BK=64 = 512).
// grid 256: bid = chunk*32 + bm*16 + bn. Partials (f32) -> Wpart[chunk].
// ---------------------------------------------------------------------------
__global__ __launch_bounds__(256)
void fold_split(const unsigned short* __restrict__ A,    // W2bf [256 x 2048]
                const unsigned short* __restrict__ B,    // W1T  [2048 x 2048]
                float* __restrict__ Wpart)               // [8][240][2048]
{
  __shared__ unsigned short sA[128 * 64];
  __shared__ unsigned short sB[128 * 64];
  const int bid = blockIdx.x;
  const int chunk = bid >> 5, rem = bid & 31;
  const int bm = rem >> 4, bn = rem & 15;
  const size_t row0 = (size_t)bm * 128, col0 = (size_t)bn * 128;
  const int tid = threadIdx.x, lane = tid & 63, wv = tid >> 6;
  const char* Ab = (const char*)(A + row0 * KD);
  const char* Bb = (const char*)(B + col0 * KD);
  const int wr = (wv >> 1) * 64, wc = (wv & 1) * 64;
  const int fr = lane & 15, fq = lane >> 4;
  f32x4 acc[4][4] = {};
  const int so = wv * 1024 + lane * 16;

  for (int kt = chunk * 4; kt < chunk * 4 + 4; ++kt) {
    const int kbyte = kt * 128;
#pragma unroll
    for (int i = 0; i < 4; ++i) {
      const int o = i * 4096 + so;
      const int r = o >> 7, cb = o & 127;
      gload_lds16(Ab + (size_t)r * (KD * 2) + kbyte + cb, (char*)sA + o);
      gload_lds16(Bb + (size_t)r * (KD * 2) + kbyte + cb, (char*)sB + o);
    }
    __syncthreads();
#pragma unroll
    for (int kk = 0; kk < 2; ++kk) {
      bf16x8 af[4], bfr[4];
#pragma unroll
      for (int m = 0; m < 4; ++m)
        af[m] = *(const bf16x8*)((const char*)sA + (wr + m * 16 + fr) * 128 + kk * 64 + fq * 16);
#pragma unroll
      for (int n = 0; n < 4; ++n)
        bfr[n] = *(const bf16x8*)((const char*)sB + (wc + n * 16 + fr) * 128 + kk * 64 + fq * 16);
#pragma unroll
      for (int m = 0; m < 4; ++m)
#pragma unroll
        for (int n = 0; n < 4; ++n)
          acc[m][n] = __builtin_amdgcn_mfma_f32_16x16x32_bf16(af[m], bfr[n], acc[m][n], 0, 0, 0);
    }
    __syncthreads();
  }

  float* Wp = Wpart + (size_t)chunk * 240 * KD;
#pragma unroll
  for (int m = 0; m < 4; ++m) {
    const size_t rb = row0 + wr + m * 16 + fq * 4;
#pragma unroll
    for (int n = 0; n < 4; ++n) {
      const int c = (int)col0 + wc + n * 16 + fr;
#pragma unroll
      for (int j = 0; j < 4; ++j) {
        const size_t r = rb + j;
        if (r < 240) Wp[r * KD + c] = acc[m][n][j];
      }
    }
  }
}

// sum 8 partials -> bf16 into Big rows 256..495; rows 496..511 zero.
__global__ __launch_bounds__(256)
void cvt_fold(const float* __restrict__ Wpart, unsigned short* __restrict__ BigHi)
{
  const int b = blockIdx.x, tid = threadIdx.x;   // b = Big row - 256
  unsigned short* dst = BigHi + (size_t)b * KD + (size_t)tid * 8;
  if (b >= 240) { *(u16x8*)dst = (u16x8){0,0,0,0,0,0,0,0}; return; }
  const size_t base = (size_t)b * KD + (size_t)tid * 8;
  float s[8] = {};
#pragma unroll
  for (int ch = 0; ch < 8; ++ch) {
    const float4* p = (const float4*)(Wpart + (size_t)ch * 240 * KD + base);
    float4 a = p[0], q = p[1];
    s[0] += a.x; s[1] += a.y; s[2] += a.z; s[3] += a.w;
    s[4] += q.x; s[5] += q.y; s[6] += q.z; s[7] += q.w;
  }
  u16x8 o;
#pragma unroll
  for (int e = 0; e < 8; ++e) o[e] = f2bf(s[e]);
  *(u16x8*)dst = o;
}

// x (f32) -> bf16 copy + per-row 1/max(||x||,eps)
__global__ __launch_bounds__(256)
void prep_x(const float* __restrict__ x, unsigned short* __restrict__ xbf,
            float* __restrict__ invn)
{
  const int n = blockIdx.x, tid = threadIdx.x;
  const float4* row = (const float4*)(x + (size_t)n * KD);
  float4 a = row[tid * 2], b = row[tid * 2 + 1];
  float ss = a.x * a.x + a.y * a.y + a.z * a.z + a.w * a.w
           + b.x * b.x + b.y * b.y + b.z * b.z + b.w * b.w;
#pragma unroll
  for (int off = 32; off > 0; off >>= 1) ss += __shfl_down(ss, off);
  __shared__ float red[4];
  if ((tid & 63) == 0) red[tid >> 6] = ss;
  __syncthreads();
  if (tid == 0) {
    const float tot = red[0] + red[1] + red[2] + red[3];
    invn[n] = 1.f / fmaxf(sqrtf(tot), 1e-8f);
  }
  u16x8 o;
  o[0] = f2bf(a.x); o[1] = f2bf(a.y); o[2] = f2bf(a.z); o[3] = f2bf(a.w);
  o[4] = f2bf(b.x); o[5] = f2bf(b.y); o[6] = f2bf(b.z); o[7] = f2bf(b.w);
  *(u16x8*)(xbf + (size_t)n * KD + (size_t)tid * 8) = o;
}

// W1T[j][i] = w1[i][j], bf16. 64x64 tiles, padded LDS.
__global__ __launch_bounds__(256)
void trans_w1(const float* __restrict__ w1, unsigned short* __restrict__ w1t)
{
  __shared__ float t[64][65];
  const int i0 = (blockIdx.x & 31) * 64;
  const int j0 = (blockIdx.x >> 5) * 64;
  const int tid = threadIdx.x;
  const int r = tid >> 4, c4 = tid & 15;
#pragma unroll
  for (int rr = 0; rr < 4; ++rr) {
    const int row = r + rr * 16;
    const float4 v = *(const float4*)(w1 + (size_t)(i0 + row) * KD + j0 + c4 * 4);
    t[row][c4 * 4 + 0] = v.x; t[row][c4 * 4 + 1] = v.y;
    t[row][c4 * 4 + 2] = v.z; t[row][c4 * 4 + 3] = v.w;
  }
  __syncthreads();
#pragma unroll
  for (int rr = 0; rr < 4; ++rr) {
    const int jrow = r + rr * 16;
    u16x4 o;
    o[0] = f2bf(t[c4 * 4 + 0][jrow]); o[1] = f2bf(t[c4 * 4 + 1][jrow]);
    o[2] = f2bf(t[c4 * 4 + 2][jrow]); o[3] = f2bf(t[c4 * 4 + 3][jrow]);
    *(u16x4*)(w1t + (size_t)(j0 + jrow) * KD + i0 + c4 * 4) = o;
  }
}

// bfold[c] = dot(w2[c], b1) + b2[c]
__global__ __launch_bounds__(256)
void bfold_k(const float* __restrict__ w2, const float* __restrict__ b1,
             const float* __restrict__ b2, float* __restrict__ bf)
{
  const int c = blockIdx.x, tid = threadIdx.x;
  const float4* row = (const float4*)(w2 + (size_t)c * KD);
  const float4* bb  = (const float4*)b1;
  float4 a = row[tid * 2], b = row[tid * 2 + 1];
  float4 p = bb[tid * 2],  q = bb[tid * 2 + 1];
  float ss = a.x * p.x + a.y * p.y + a.z * p.z + a.w * p.w
           + b.x * q.x + b.y * q.y + b.z * q.z + b.w * q.w;
#pragma unroll
  for (int off = 32; off > 0; off >>= 1) ss += __shfl_down(ss, off);
  __shared__ float red[4];
  if ((tid & 63) == 0) red[tid >> 6] = ss;
  __syncthreads();
  if (tid == 0) bf[c] = red[0] + red[1] + red[2] + red[3] + b2[c];
}

// blocks 0..255: Big rows 0..255 (rn/nrn normalized, pad 240..255 zero)
// blocks 256..511: W2bf rows (bbox_w bf16, pad zero)
__global__ __launch_bounds__(256)
void prep_rows(const float* __restrict__ reps, const float* __restrict__ negrep,
               const float* __restrict__ bbox,
               unsigned short* __restrict__ Big, unsigned short* __restrict__ W2)
{
  const int r = blockIdx.x, tid = threadIdx.x;
  const u16x8 z = {0, 0, 0, 0, 0, 0, 0, 0};
  if (r < 256) {
    unsigned short* dst = Big + (size_t)r * KD;
    if (r >= 240) { *(u16x8*)(dst + (size_t)tid * 8) = z; return; }
    const float* src = (r < 60) ? reps + (size_t)r * KD
                                : negrep + (size_t)(r - 60) * KD;
    const float4* p = (const float4*)src;
    float4 a = p[tid * 2], b = p[tid * 2 + 1];
    float ss = a.x * a.x + a.y * a.y + a.z * a.z + a.w * a.w
             + b.x * b.x + b.y * b.y + b.z * b.z + b.w * b.w;
#pragma unroll
    for (int off = 32; off > 0; off >>= 1) ss += __shfl_down(ss, off);
    __shared__ float red[4];
    if ((tid & 63) == 0) red[tid >> 6] = ss;
    __syncthreads();
    const float iv = 1.f / fmaxf(sqrtf(red[0] + red[1] + red[2] + red[3]), 1e-8f);
    u16x8 o;
    o[0] = f2bf(a.x * iv); o[1] = f2bf(a.y * iv); o[2] = f2bf(a.z * iv); o[3] = f2bf(a.w * iv);
    o[4] = f2bf(b.x * iv); o[5] = f2bf(b.y * iv); o[6] = f2bf(b.z * iv); o[7] = f2bf(b.w * iv);
    *(u16x8*)(dst + (size_t)tid * 8) = o;
  } else {
    const int rr = r - 256;
    unsigned short* dst = W2 + (size_t)rr * KD;
    if (rr >= 240) { *(u16x8*)(dst + (size_t)tid * 8) = z; return; }
    const float4* p = (const float4*)(bbox + (size_t)rr * KD);
    float4 a = p[tid * 2], b = p[tid * 2 + 1];
    u16x8 o;
    o[0] = f2bf(a.x); o[1] = f2bf(a.y); o[2] = f2bf(a.z); o[3] = f2bf(a.w);
    o[4] = f2bf(b.x); o[5] = f2bf(b.y); o[6] = f2bf(b.z); o[7] = f2bf(b.w);
    *(u16x8*)(dst + (size_t)tid * 8) = o;
  }
}

extern "C" void kernel_launch(void* const* d_in, const int* in_sizes, int n_in,
                              void* d_out, int out_size, void* d_ws, size_t ws_size,
                              hipStream_t stream)
{
  const float* x      = (const float*)d_in[0];
  const float* reps   = (const float*)d_in[1];
  const float* negrep = (const float*)d_in[2];
  const float* w1     = (const float*)d_in[3];
  const float* b1     = (const float*)d_in[4];
  const float* w2     = (const float*)d_in[5];
  const float* b2     = (const float*)d_in[6];
  float* out = (float*)d_out;

  // ws carve — ~90.1 MiB total
  char* w = (char*)d_ws;
  unsigned short* Big  = (unsigned short*)(w);             // 2 MiB  (512 x 2048)
  unsigned short* W1T  = (unsigned short*)(w + 2097152);   // 8 MiB
  unsigned short* W2bf = (unsigned short*)(w + 10485760);  // 1 MiB
  float*          invn = (float*)(w + 11534336);           // 64 KiB
  float*          bfold= (float*)(w + 11599872);           // 4 KiB
  float*          Wpart= (float*)(w + 11603968);           // 15 MiB (8 x 240 x 2048)
  unsigned short* xbf  = (unsigned short*)(w + 27332608);  // 64 MiB (end 94441472)

  prep_x   <<<NROWS, 256, 0, stream>>>(x, xbf, invn);
  trans_w1 <<<1024, 256, 0, stream>>>(w1, W1T);
  prep_rows<<<512, 256, 0, stream>>>(reps, negrep, w2, Big, W2bf);
  bfold_k  <<<240, 256, 0, stream>>>(w2, b1, b2, bfold);

  // Wfold = W2 @ W1, K split 8-ways -> Wpart, then reduce+cvt into Big rows 256..511
  fold_split<<<256, 256, 0, stream>>>(W2bf, W1T, Wpart);
  cvt_fold  <<<256, 256, 0, stream>>>(Wpart, Big + 256 * (size_t)KD);

  // one pass over x: S-block (post fused) + deltas
  gemm256<<<128 * 2, 512, 0, stream>>>(xbf, Big, out, invn, bfold);
}